// Round 15
// baseline (121.521 us; speedup 1.0000x reference)
//
#include <hip/hip_runtime.h>
#include <hip/hip_bf16.h>

#define NNODES 4096
#define CAP 256

// R11: grid.sync ~100+us -> dispatches. R13: per-node W1 re-read = 536MB.
// R14: unfused D3 at 1 block/CU + h0 round-trip ate the gain.
// R15: re-fuse gemm1 amortized over 8 nodes/block (W1 traffic 67MB), and
// issue gemm0 blocks first in phase1 for true overlap.

// ---------------------------------------------------------------------------
// Phase 1: blocks [0,1024) = layer-0 GEMM tiles (+scores0) — issued FIRST so
// they overlap under the HBM-bound mask scan; blocks [1024,5120) = edge rows.
// ---------------------------------------------------------------------------
__global__ __launch_bounds__(256) void phase1_kernel(
    const float* __restrict__ mask, int* __restrict__ deg, int* __restrict__ cols,
    const float* __restrict__ x, const float* __restrict__ W0,
    const float* __restrict__ b0, const float* __restrict__ a_src0,
    const float* __restrict__ a_tgt0, float* __restrict__ proj0,
    float* __restrict__ ssrc0, float* __restrict__ stgt0) {
  __shared__ float smem[32 * 36 + 32 * 64];
  const int t = threadIdx.x;
  if (blockIdx.x >= 1024) {
    const int n = blockIdx.x - 1024;
    const int lane = t & 63, wid = t >> 6;
    int* wsum = (int*)smem;
    const float4* row = (const float4*)(mask + (size_t)n * NNODES);
    float4 v[4];
    int cnt = 0;
#pragma unroll
    for (int j = 0; j < 4; ++j) {
      v[j] = row[t + 256 * j];  // coalesced
      cnt += (v[j].x == 0.0f) + (v[j].y == 0.0f) + (v[j].z == 0.0f) +
             (v[j].w == 0.0f);
    }
    int xs = cnt;
#pragma unroll
    for (int o = 1; o < 64; o <<= 1) {
      int y = __shfl_up(xs, o);
      if (lane >= o) xs += y;
    }
    if (lane == 63) wsum[wid] = xs;
    __syncthreads();
    int base = 0;
    for (int w = 0; w < wid; ++w) base += wsum[w];
    int off = base + xs - cnt;
    if (t == 0) {
      int total = wsum[0] + wsum[1] + wsum[2] + wsum[3];
      deg[n] = total < CAP ? total : CAP;
    }
    int* dst = cols + (size_t)n * CAP;
#pragma unroll
    for (int j = 0; j < 4; ++j) {
      const int c0 = (t + 256 * j) * 4;
      float fv[4] = {v[j].x, v[j].y, v[j].z, v[j].w};
#pragma unroll
      for (int k = 0; k < 4; ++k) {
        if (fv[k] == 0.0f) {
          if (off < CAP) dst[off] = c0 + k;
          ++off;
        }
      }
    }
  } else {
    // gemm0: 32x64 tile, K=128, BK=32 chunks, 2x4 reg blocking + scores0
    float(*As)[36] = (float(*)[36])smem;
    float(*Ws)[64] = (float(*)[64])(smem + 32 * 36);
    const int bx = blockIdx.x;
    const int brow = (bx & 127) * 32;
    const int head = bx >> 7;
    const int bcol = head * 64;
    const int tx = t & 15, ty = t >> 4;
    const int ar = t >> 3, ak = (t & 7) * 4;
    float acc[2][4] = {};
    for (int c = 0; c < 4; ++c) {
      const int k0 = c * 32;
      *(float4*)&As[ar][ak] =
          *(const float4*)&x[(size_t)(brow + ar) * 128 + k0 + ak];
#pragma unroll
      for (int q = 0; q < 2; ++q) {
        int i = t + q * 256;
        int k = i >> 4, c4 = (i & 15) * 4;
        *(float4*)&Ws[k][c4] =
            *(const float4*)&W0[(size_t)(k0 + k) * 512 + bcol + c4];
      }
      __syncthreads();
#pragma unroll 2
      for (int kk = 0; kk < 32; kk += 4) {
        float4 a0 = *(const float4*)&As[ty * 2 + 0][kk];
        float4 a1 = *(const float4*)&As[ty * 2 + 1][kk];
#pragma unroll
        for (int j = 0; j < 4; ++j) {
          float4 w = *(const float4*)&Ws[kk + j][tx * 4];
          float av0 = ((const float*)&a0)[j];
          float av1 = ((const float*)&a1)[j];
          acc[0][0] = fmaf(av0, w.x, acc[0][0]);
          acc[0][1] = fmaf(av0, w.y, acc[0][1]);
          acc[0][2] = fmaf(av0, w.z, acc[0][2]);
          acc[0][3] = fmaf(av0, w.w, acc[0][3]);
          acc[1][0] = fmaf(av1, w.x, acc[1][0]);
          acc[1][1] = fmaf(av1, w.y, acc[1][1]);
          acc[1][2] = fmaf(av1, w.z, acc[1][2]);
          acc[1][3] = fmaf(av1, w.w, acc[1][3]);
        }
      }
      __syncthreads();
    }
    const float4 bv = *(const float4*)&b0[bcol + tx * 4];
    const float4 as = *(const float4*)&a_src0[head * 64 + tx * 4];
    const float4 at = *(const float4*)&a_tgt0[head * 64 + tx * 4];
#pragma unroll
    for (int r = 0; r < 2; ++r) {
      float4 o;
      o.x = acc[r][0] + bv.x; o.y = acc[r][1] + bv.y;
      o.z = acc[r][2] + bv.z; o.w = acc[r][3] + bv.w;
      const size_t node = brow + ty * 2 + r;
      *(float4*)&proj0[node * 512 + bcol + tx * 4] = o;
      float ps = o.x * as.x + o.y * as.y + o.z * as.z + o.w * as.w;
      float pt = o.x * at.x + o.y * at.y + o.z * at.z + o.w * at.w;
#pragma unroll
      for (int m = 8; m; m >>= 1) {
        ps += __shfl_xor(ps, m);
        pt += __shfl_xor(pt, m);
      }
      if (tx == 0) {
        ssrc0[node * 8 + head] = ps;
        stgt0[node * 8 + head] = pt;
      }
    }
  }
}

// ---------------------------------------------------------------------------
// D2: 8 nodes per block. Per node: attn layer 0 (H=8) -> h0rows[ni] in LDS.
// Then one 8x512 @ 512x64 mini-GEMM (W1 staged in 32KB chunks, amortized over
// the 8 nodes: W1 L2 traffic = 512 x 131KB = 67MB, not 4096x = 536MB) with
// fused bias + scores1. Eliminates h0 global round-trip and one dispatch.
// Static LDS = 60.0 KB -> 2 blocks/CU.
// ---------------------------------------------------------------------------
__global__ __launch_bounds__(256) void attn8_gemm1_v2(
    const float* __restrict__ proj0, const float* __restrict__ ssrc0,
    const float* __restrict__ stgt0, const int* __restrict__ deg,
    const int* __restrict__ cols, const float* __restrict__ W1,
    const float* __restrict__ b1, const float* __restrict__ a_src1,
    const float* __restrict__ a_tgt1, float* __restrict__ proj1,
    float* __restrict__ ssrc1, float* __restrict__ stgt1) {
  const int t = threadIdx.x;
  const int lane = t & 63, wid = t >> 6;
  __shared__ int sm_[CAP];           // 1 KB
  __shared__ float sw[CAP * 9];      // 9.2 KB (stride 9: conflict-free)
  __shared__ float sinv[8];
  __shared__ float h0rows[8][512];   // 16 KB
  __shared__ float Ws[128][64];      // 32 KB
  __shared__ float4 buf[128];        // 2 KB
  const int nbase = blockIdx.x * 8;

  for (int ni = 0; ni < 8; ++ni) {
    const int n = nbase + ni;
    const int d = deg[n];
    for (int i = t; i < d; i += 256) sm_[i] = cols[(size_t)n * CAP + i];
    __syncthreads();
    for (int i = t; i < d * 8; i += 256) {
      int e = i >> 3, h = i & 7;
      float s = ssrc0[n * 8 + h] + stgt0[sm_[e] * 8 + h];
      sw[e * 9 + h] = s >= 0.f ? s : 0.2f * s;
    }
    __syncthreads();
    for (int h = wid; h < 8; h += 4) {  // each wave owns its heads (no race)
      float mx = -1e30f;
      for (int e = lane; e < d; e += 64) mx = fmaxf(mx, sw[e * 9 + h]);
#pragma unroll
      for (int o = 32; o; o >>= 1) mx = fmaxf(mx, __shfl_xor(mx, o));
      float sum = 0.f;
      for (int e = lane; e < d; e += 64) {
        float w = __expf(sw[e * 9 + h] - mx);
        sw[e * 9 + h] = w;
        sum += w;
      }
#pragma unroll
      for (int o = 32; o; o >>= 1) sum += __shfl_xor(sum, o);
      if (lane == 0) sinv[h] = 1.0f / sum;
    }
    __syncthreads();
    // gather: 128 float4 outputs, 2-way edge split (R13: keep ILP simple)
    const int f4 = t & 127, grp = t >> 7;
    const int hh = f4 >> 4;
    float4 acc = make_float4(0.f, 0.f, 0.f, 0.f);
    for (int e = grp; e < d; e += 2) {
      const float w = sw[e * 9 + hh];
      const float4 pv = *(const float4*)&proj0[(size_t)sm_[e] * 512 + f4 * 4];
      acc.x = fmaf(w, pv.x, acc.x);
      acc.y = fmaf(w, pv.y, acc.y);
      acc.z = fmaf(w, pv.z, acc.z);
      acc.w = fmaf(w, pv.w, acc.w);
    }
    if (grp == 1) buf[f4] = acc;
    __syncthreads();
    if (grp == 0) {
      const float4 o2 = buf[f4];
      const float s = sinv[hh];
      float4 o;
      o.x = (acc.x + o2.x) * s;
      o.y = (acc.y + o2.y) * s;
      o.z = (acc.z + o2.z) * s;
      o.w = (acc.w + o2.w) * s;
      *(float4*)&h0rows[ni][f4 * 4] = o;
    }
    __syncthreads();  // sm_/sw reuse by next node
  }

  // mini-GEMM: 8 rows x K=512 @ W1(512x64). rg = t>>6 handles rows rg*2,+1;
  // lane = output col. h0rows reads are wave-broadcast; Ws[k][lane] 2-way free.
  const int rg = t >> 6;
  float acc0 = 0.f, acc1 = 0.f;
  for (int c = 0; c < 4; ++c) {
    for (int i = t; i < 2048; i += 256) {
      const int k = i >> 4, c4 = (i & 15) * 4;
      *(float4*)&Ws[k][c4] =
          *(const float4*)&W1[(size_t)(c * 128 + k) * 64 + c4];
    }
    __syncthreads();
#pragma unroll 4
    for (int k = 0; k < 128; ++k) {
      const float w = Ws[k][lane];
      acc0 = fmaf(h0rows[rg * 2 + 0][c * 128 + k], w, acc0);
      acc1 = fmaf(h0rows[rg * 2 + 1][c * 128 + k], w, acc1);
    }
    __syncthreads();
  }
  const float bb = b1[lane];
  const float as = a_src1[lane];
  const float at = a_tgt1[lane];
#pragma unroll
  for (int r = 0; r < 2; ++r) {
    const int node = nbase + rg * 2 + r;
    const float v = (r == 0 ? acc0 : acc1) + bb;
    proj1[(size_t)node * 64 + lane] = v;
    float ps = v * as;
    float pt = v * at;
#pragma unroll
    for (int o = 32; o; o >>= 1) {
      ps += __shfl_xor(ps, o);
      pt += __shfl_xor(pt, o);
    }
    if (lane == 0) {
      ssrc1[node] = ps;
      stgt1[node] = pt;
    }
  }
}

// ---------------------------------------------------------------------------
// D3: attn layer 1 (H=1): one wave per node; float4 gather, 4-way edge split.
// proj1 = 1MB -> L2-resident, fast.
// ---------------------------------------------------------------------------
__global__ void attn1_kernel(
    const float* __restrict__ proj, const float* __restrict__ s_src,
    const float* __restrict__ s_tgt, const int* __restrict__ deg,
    const int* __restrict__ cols, float* __restrict__ out) {
  const int n = blockIdx.x;
  const int tid = threadIdx.x;  // 64 threads = 1 wave
  __shared__ int sm_[CAP];
  __shared__ float sw[CAP];
  const int d = deg[n];
  for (int i = tid; i < d; i += 64) sm_[i] = cols[(size_t)n * CAP + i];
  __syncthreads();
  const float ssn = s_src[n];
  for (int i = tid; i < d; i += 64) {
    float s = ssn + s_tgt[sm_[i]];
    sw[i] = s >= 0.f ? s : 0.2f * s;
  }
  __syncthreads();
  float mx = -1e30f;
  for (int e = tid; e < d; e += 64) mx = fmaxf(mx, sw[e]);
#pragma unroll
  for (int o = 32; o; o >>= 1) mx = fmaxf(mx, __shfl_xor(mx, o));
  float sum = 0.f;
  for (int e = tid; e < d; e += 64) {
    float w = __expf(sw[e] - mx);
    sw[e] = w;
    sum += w;
  }
#pragma unroll
  for (int o = 32; o; o >>= 1) sum += __shfl_xor(sum, o);
  const float sinv = 1.0f / sum;
  __syncthreads();
  const int f4 = tid & 15, grp = tid >> 4;  // 16 float4 outputs, 4-way edges
  float4 acc = make_float4(0.f, 0.f, 0.f, 0.f);
  for (int e = grp; e < d; e += 4) {
    const float w = sw[e];
    const float4 pv = *(const float4*)&proj[(size_t)sm_[e] * 64 + f4 * 4];
    acc.x = fmaf(w, pv.x, acc.x);
    acc.y = fmaf(w, pv.y, acc.y);
    acc.z = fmaf(w, pv.z, acc.z);
    acc.w = fmaf(w, pv.w, acc.w);
  }
#pragma unroll
  for (int o = 16; o <= 32; o <<= 1) {
    acc.x += __shfl_xor(acc.x, o);
    acc.y += __shfl_xor(acc.y, o);
    acc.z += __shfl_xor(acc.z, o);
    acc.w += __shfl_xor(acc.w, o);
  }
  if (grp == 0) {
    acc.x *= sinv; acc.y *= sinv; acc.z *= sinv; acc.w *= sinv;
    *(float4*)&out[(size_t)n * 64 + f4 * 4] = acc;
  }
}

// ---------------------------------------------------------------------------
extern "C" void kernel_launch(void* const* d_in, const int* in_sizes, int n_in,
                              void* d_out, int out_size, void* d_ws, size_t ws_size,
                              hipStream_t stream) {
  const float* x      = (const float*)d_in[0];
  const float* mask   = (const float*)d_in[1];
  const float* W0     = (const float*)d_in[2];
  const float* b0     = (const float*)d_in[3];
  const float* a_src0 = (const float*)d_in[4];
  const float* a_tgt0 = (const float*)d_in[5];
  const float* W1     = (const float*)d_in[6];
  const float* b1     = (const float*)d_in[7];
  const float* a_src1 = (const float*)d_in[8];
  const float* a_tgt1 = (const float*)d_in[9];
  float* out = (float*)d_out;

  // workspace layout (~13.4 MB)
  float* ws    = (float*)d_ws;
  float* proj0 = ws;                          // 4096*512
  float* proj1 = proj0 + NNODES * 512;        // 4096*64
  float* ssrc0 = proj1 + NNODES * 64;         // 4096*8
  float* stgt0 = ssrc0 + NNODES * 8;          // 4096*8
  float* ssrc1 = stgt0 + NNODES * 8;          // 4096
  float* stgt1 = ssrc1 + NNODES;              // 4096
  int* deg  = (int*)(stgt1 + NNODES);         // 4096
  int* cols = deg + NNODES;                   // 4096*CAP

  // D1: gemm0+scores0 (first 1024 blocks, overlap) + edge extraction (4096)
  phase1_kernel<<<NNODES + 1024, 256, 0, stream>>>(
      mask, deg, cols, x, W0, b0, a_src0, a_tgt0, proj0, ssrc0, stgt0);
  // D2: attn0 (8 nodes/block) + amortized gemm1 + bias + scores1
  attn8_gemm1_v2<<<NNODES / 8, 256, 0, stream>>>(
      proj0, ssrc0, stgt0, deg, cols, W1, b1, a_src1, a_tgt1,
      proj1, ssrc1, stgt1);
  // D3: attn layer 1
  attn1_kernel<<<NNODES, 64, 0, stream>>>(proj1, ssrc1, stgt1, deg, cols, out);
}

// Round 16
// 69.384 us; speedup vs baseline: 1.7514x; 1.7514x over previous
//
#include <hip/hip_runtime.h>
#include <hip/hip_bf16.h>

#define NNODES 4096
#define CAP 256

// Ledger: R11 grid.sync ~100us -> dispatches. R13 per-node W1 = 536MB. R15
// 8-node amortize -> 2 blocks/CU, no latency hiding (94us). R8 structure
// (5 dispatches) = best at 76.8. R16: head-half XCD split so each XCD's
// gather working set (4MB half of proj0) fits its private L2.

// ---------------------------------------------------------------------------
// Phase 1: blocks [0,1024) = layer-0 GEMM tiles (+scores0) issued FIRST
// (overlap under mask scan); blocks [1024,5120) = edge extraction rows.
// ---------------------------------------------------------------------------
__global__ __launch_bounds__(256) void phase1_kernel(
    const float* __restrict__ mask, int* __restrict__ deg, int* __restrict__ cols,
    const float* __restrict__ x, const float* __restrict__ W0,
    const float* __restrict__ b0, const float* __restrict__ a_src0,
    const float* __restrict__ a_tgt0, float* __restrict__ proj0,
    float* __restrict__ ssrc0, float* __restrict__ stgt0) {
  __shared__ float smem[32 * 36 + 32 * 64];
  const int t = threadIdx.x;
  if (blockIdx.x >= 1024) {
    const int n = blockIdx.x - 1024;
    const int lane = t & 63, wid = t >> 6;
    int* wsum = (int*)smem;
    const float4* row = (const float4*)(mask + (size_t)n * NNODES);
    float4 v[4];
    int cnt = 0;
#pragma unroll
    for (int j = 0; j < 4; ++j) {
      v[j] = row[t + 256 * j];  // coalesced
      cnt += (v[j].x == 0.0f) + (v[j].y == 0.0f) + (v[j].z == 0.0f) +
             (v[j].w == 0.0f);
    }
    int xs = cnt;
#pragma unroll
    for (int o = 1; o < 64; o <<= 1) {
      int y = __shfl_up(xs, o);
      if (lane >= o) xs += y;
    }
    if (lane == 63) wsum[wid] = xs;
    __syncthreads();
    int base = 0;
    for (int w = 0; w < wid; ++w) base += wsum[w];
    int off = base + xs - cnt;
    if (t == 0) {
      int total = wsum[0] + wsum[1] + wsum[2] + wsum[3];
      deg[n] = total < CAP ? total : CAP;
    }
    int* dst = cols + (size_t)n * CAP;
#pragma unroll
    for (int j = 0; j < 4; ++j) {
      const int c0 = (t + 256 * j) * 4;
      float fv[4] = {v[j].x, v[j].y, v[j].z, v[j].w};
#pragma unroll
      for (int k = 0; k < 4; ++k) {
        if (fv[k] == 0.0f) {
          if (off < CAP) dst[off] = c0 + k;
          ++off;
        }
      }
    }
  } else {
    // gemm0: 32x64 tile, K=128, BK=32 chunks, 2x4 reg blocking + scores0
    float(*As)[36] = (float(*)[36])smem;
    float(*Ws)[64] = (float(*)[64])(smem + 32 * 36);
    const int bx = blockIdx.x;
    const int brow = (bx & 127) * 32;
    const int head = bx >> 7;
    const int bcol = head * 64;
    const int tx = t & 15, ty = t >> 4;
    const int ar = t >> 3, ak = (t & 7) * 4;
    float acc[2][4] = {};
    for (int c = 0; c < 4; ++c) {
      const int k0 = c * 32;
      *(float4*)&As[ar][ak] =
          *(const float4*)&x[(size_t)(brow + ar) * 128 + k0 + ak];
#pragma unroll
      for (int q = 0; q < 2; ++q) {
        int i = t + q * 256;
        int k = i >> 4, c4 = (i & 15) * 4;
        *(float4*)&Ws[k][c4] =
            *(const float4*)&W0[(size_t)(k0 + k) * 512 + bcol + c4];
      }
      __syncthreads();
#pragma unroll 2
      for (int kk = 0; kk < 32; kk += 4) {
        float4 a0 = *(const float4*)&As[ty * 2 + 0][kk];
        float4 a1 = *(const float4*)&As[ty * 2 + 1][kk];
#pragma unroll
        for (int j = 0; j < 4; ++j) {
          float4 w = *(const float4*)&Ws[kk + j][tx * 4];
          float av0 = ((const float*)&a0)[j];
          float av1 = ((const float*)&a1)[j];
          acc[0][0] = fmaf(av0, w.x, acc[0][0]);
          acc[0][1] = fmaf(av0, w.y, acc[0][1]);
          acc[0][2] = fmaf(av0, w.z, acc[0][2]);
          acc[0][3] = fmaf(av0, w.w, acc[0][3]);
          acc[1][0] = fmaf(av1, w.x, acc[1][0]);
          acc[1][1] = fmaf(av1, w.y, acc[1][1]);
          acc[1][2] = fmaf(av1, w.z, acc[1][2]);
          acc[1][3] = fmaf(av1, w.w, acc[1][3]);
        }
      }
      __syncthreads();
    }
    const float4 bv = *(const float4*)&b0[bcol + tx * 4];
    const float4 as = *(const float4*)&a_src0[head * 64 + tx * 4];
    const float4 at = *(const float4*)&a_tgt0[head * 64 + tx * 4];
#pragma unroll
    for (int r = 0; r < 2; ++r) {
      float4 o;
      o.x = acc[r][0] + bv.x; o.y = acc[r][1] + bv.y;
      o.z = acc[r][2] + bv.z; o.w = acc[r][3] + bv.w;
      const size_t node = brow + ty * 2 + r;
      *(float4*)&proj0[node * 512 + bcol + tx * 4] = o;
      float ps = o.x * as.x + o.y * as.y + o.z * as.z + o.w * as.w;
      float pt = o.x * at.x + o.y * at.y + o.z * at.z + o.w * at.w;
#pragma unroll
      for (int m = 8; m; m >>= 1) {
        ps += __shfl_xor(ps, m);
        pt += __shfl_xor(pt, m);
      }
      if (tx == 0) {
        ssrc0[node * 8 + head] = ps;
        stgt0[node * 8 + head] = pt;
      }
    }
  }
}

// ---------------------------------------------------------------------------
// D2: attn layer 0, head-half split for XCD L2 residency.
// Block b: xcd=b&7, fh=(b&7)>>2 (head-half), n=(b>>3)*4+(b&3)  [bijective].
// XCDs 0-3 gather only proj0[:,0:256] (4MB = one XCD L2); XCDs 4-7 the rest.
// 128 threads, 7.2KB LDS -> high occupancy; 8192 blocks.
// ---------------------------------------------------------------------------
__global__ __launch_bounds__(128) void attn8h_kernel(
    const float* __restrict__ proj0, const float* __restrict__ ssrc0,
    const float* __restrict__ stgt0, const int* __restrict__ deg,
    const int* __restrict__ cols, float* __restrict__ h0) {
  const int b = blockIdx.x;
  const int fh = (b & 7) >> 2;          // head-half, tied to XCD group
  const int n = ((b >> 3) << 2) + (b & 3);
  const int t = threadIdx.x;            // 128 threads = 2 waves
  const int lane = t & 63, wid = t >> 6;
  __shared__ int sm_[CAP];              // 1 KB
  __shared__ float sw[CAP * 5];         // 5 KB, stride 5 (coprime 32)
  __shared__ float sinv[4];
  __shared__ float4 buf[64];            // 1 KB
  const int d = deg[n];
  for (int i = t; i < d; i += 128) sm_[i] = cols[(size_t)n * CAP + i];
  __syncthreads();
  const int hbase = fh * 4;
  for (int i = t; i < d * 4; i += 128) {
    const int e = i >> 2, h = i & 3;
    float s = ssrc0[n * 8 + hbase + h] + stgt0[sm_[e] * 8 + hbase + h];
    sw[e * 5 + h] = s >= 0.f ? s : 0.2f * s;
  }
  __syncthreads();
  for (int h = wid; h < 4; h += 2) {  // wave owns local heads h, h+2 (no race)
    float mx = -1e30f;
    for (int e = lane; e < d; e += 64) mx = fmaxf(mx, sw[e * 5 + h]);
#pragma unroll
    for (int o = 32; o; o >>= 1) mx = fmaxf(mx, __shfl_xor(mx, o));
    float sum = 0.f;
    for (int e = lane; e < d; e += 64) {
      float w = __expf(sw[e * 5 + h] - mx);
      sw[e * 5 + h] = w;
      sum += w;
    }
#pragma unroll
    for (int o = 32; o; o >>= 1) sum += __shfl_xor(sum, o);
    if (lane == 0) sinv[h] = 1.0f / sum;
  }
  __syncthreads();
  // gather: 64 float4 outputs (4 heads x 16), 2-way edge split
  const int f4l = t & 63, grp = t >> 6;
  const int hl = f4l >> 4;  // local head 0..3
  float4 acc = make_float4(0.f, 0.f, 0.f, 0.f);
  for (int e = grp; e < d; e += 2) {
    const float w = sw[e * 5 + hl];
    const float4 pv =
        *(const float4*)&proj0[(size_t)sm_[e] * 512 + fh * 256 + f4l * 4];
    acc.x = fmaf(w, pv.x, acc.x);
    acc.y = fmaf(w, pv.y, acc.y);
    acc.z = fmaf(w, pv.z, acc.z);
    acc.w = fmaf(w, pv.w, acc.w);
  }
  if (grp == 1) buf[f4l] = acc;
  __syncthreads();
  if (grp == 0) {
    const float4 o2 = buf[f4l];
    const float s = sinv[hl];
    float4 o;
    o.x = (acc.x + o2.x) * s;
    o.y = (acc.y + o2.y) * s;
    o.z = (acc.z + o2.z) * s;
    o.w = (acc.w + o2.w) * s;
    *(float4*)&h0[(size_t)n * 512 + fh * 256 + f4l * 4] = o;
  }
}

// ---------------------------------------------------------------------------
// D3: fp32 GEMM 32x64 tile, 128-K z-planes (split-K), BK=32, 2x4 reg block.
// (R8's proven gemm1; bias deferred to reduce.) grid (M/32, 1, 4)
// ---------------------------------------------------------------------------
__global__ __launch_bounds__(256) void gemm32x64_v2(
    const float* __restrict__ A, int lda, const float* __restrict__ W, int ldw,
    float* __restrict__ C, int ldc) {
  __shared__ float As[32][36];
  __shared__ float Ws[32][64];
  const int t = threadIdx.x;
  const int brow = blockIdx.x * 32;
  const int bcol = blockIdx.y * 64;
  const int k0base = blockIdx.z * 128;
  C += (size_t)blockIdx.z * gridDim.x * 32 * ldc;  // split-K partial plane
  const int tx = t & 15, ty = t >> 4;
  const int ar = t >> 3, ak = (t & 7) * 4;
  float acc[2][4] = {};
  for (int c = 0; c < 4; ++c) {
    const int k0 = k0base + c * 32;
    *(float4*)&As[ar][ak] = *(const float4*)&A[(size_t)(brow + ar) * lda + k0 + ak];
#pragma unroll
    for (int q = 0; q < 2; ++q) {
      int i = t + q * 256;
      int k = i >> 4, c4 = (i & 15) * 4;
      *(float4*)&Ws[k][c4] = *(const float4*)&W[(size_t)(k0 + k) * ldw + bcol + c4];
    }
    __syncthreads();
#pragma unroll 2
    for (int kk = 0; kk < 32; kk += 4) {
      float4 a0 = *(const float4*)&As[ty * 2 + 0][kk];
      float4 a1 = *(const float4*)&As[ty * 2 + 1][kk];
#pragma unroll
      for (int j = 0; j < 4; ++j) {
        float4 w = *(const float4*)&Ws[kk + j][tx * 4];
        float av0 = ((const float*)&a0)[j];
        float av1 = ((const float*)&a1)[j];
        acc[0][0] = fmaf(av0, w.x, acc[0][0]);
        acc[0][1] = fmaf(av0, w.y, acc[0][1]);
        acc[0][2] = fmaf(av0, w.z, acc[0][2]);
        acc[0][3] = fmaf(av0, w.w, acc[0][3]);
        acc[1][0] = fmaf(av1, w.x, acc[1][0]);
        acc[1][1] = fmaf(av1, w.y, acc[1][1]);
        acc[1][2] = fmaf(av1, w.z, acc[1][2]);
        acc[1][3] = fmaf(av1, w.w, acc[1][3]);
      }
    }
    __syncthreads();
  }
#pragma unroll
  for (int r = 0; r < 2; ++r) {
    float4 o;
    o.x = acc[r][0]; o.y = acc[r][1]; o.z = acc[r][2]; o.w = acc[r][3];
    *(float4*)&C[(size_t)(brow + ty * 2 + r) * ldc + bcol + tx * 4] = o;
  }
}

// ---------------------------------------------------------------------------
// D4: sum 4 split-K partials + bias -> proj1, fused scores1 (16-lane reduce).
// ---------------------------------------------------------------------------
__global__ __launch_bounds__(256) void reduce_scores1_kernel(
    const float* __restrict__ part, const float* __restrict__ bias,
    const float* __restrict__ a_src1, const float* __restrict__ a_tgt1,
    float* __restrict__ proj1, float* __restrict__ ssrc1,
    float* __restrict__ stgt1) {
  const int i = blockIdx.x * 256 + threadIdx.x;  // float4 idx, 65536 total
  const float4* p = (const float4*)part;
  float4 a = p[i], b = p[i + 65536], c = p[i + 131072], d = p[i + 196608];
  const int f4 = i & 15;
  const float4 bb = *(const float4*)&bias[f4 * 4];
  float4 r;
  r.x = a.x + b.x + c.x + d.x + bb.x;
  r.y = a.y + b.y + c.y + d.y + bb.y;
  r.z = a.z + b.z + c.z + d.z + bb.z;
  r.w = a.w + b.w + c.w + d.w + bb.w;
  ((float4*)proj1)[i] = r;
  const float4 as = *(const float4*)&a_src1[f4 * 4];
  const float4 at = *(const float4*)&a_tgt1[f4 * 4];
  float ps = r.x * as.x + r.y * as.y + r.z * as.z + r.w * as.w;
  float pt = r.x * at.x + r.y * at.y + r.z * at.z + r.w * at.w;
#pragma unroll
  for (int m = 8; m; m >>= 1) {
    ps += __shfl_xor(ps, m);
    pt += __shfl_xor(pt, m);
  }
  if (f4 == 0) {
    const int node = i >> 4;
    ssrc1[node] = ps;
    stgt1[node] = pt;
  }
}

// ---------------------------------------------------------------------------
// D5: attn layer 1 (H=1): one wave per node; float4 gather, 4-way edge split.
// ---------------------------------------------------------------------------
__global__ void attn1_kernel(
    const float* __restrict__ proj, const float* __restrict__ s_src,
    const float* __restrict__ s_tgt, const int* __restrict__ deg,
    const int* __restrict__ cols, float* __restrict__ out) {
  const int n = blockIdx.x;
  const int tid = threadIdx.x;  // 64 threads = 1 wave
  __shared__ int sm_[CAP];
  __shared__ float sw[CAP];
  const int d = deg[n];
  for (int i = tid; i < d; i += 64) sm_[i] = cols[(size_t)n * CAP + i];
  __syncthreads();
  const float ssn = s_src[n];
  for (int i = tid; i < d; i += 64) {
    float s = ssn + s_tgt[sm_[i]];
    sw[i] = s >= 0.f ? s : 0.2f * s;
  }
  __syncthreads();
  float mx = -1e30f;
  for (int e = tid; e < d; e += 64) mx = fmaxf(mx, sw[e]);
#pragma unroll
  for (int o = 32; o; o >>= 1) mx = fmaxf(mx, __shfl_xor(mx, o));
  float sum = 0.f;
  for (int e = tid; e < d; e += 64) {
    float w = __expf(sw[e] - mx);
    sw[e] = w;
    sum += w;
  }
#pragma unroll
  for (int o = 32; o; o >>= 1) sum += __shfl_xor(sum, o);
  const float sinv = 1.0f / sum;
  __syncthreads();
  const int f4 = tid & 15, grp = tid >> 4;  // 16 float4 outputs, 4-way edges
  float4 acc = make_float4(0.f, 0.f, 0.f, 0.f);
  for (int e = grp; e < d; e += 4) {
    const float w = sw[e];
    const float4 pv = *(const float4*)&proj[(size_t)sm_[e] * 64 + f4 * 4];
    acc.x = fmaf(w, pv.x, acc.x);
    acc.y = fmaf(w, pv.y, acc.y);
    acc.z = fmaf(w, pv.z, acc.z);
    acc.w = fmaf(w, pv.w, acc.w);
  }
#pragma unroll
  for (int o = 16; o <= 32; o <<= 1) {
    acc.x += __shfl_xor(acc.x, o);
    acc.y += __shfl_xor(acc.y, o);
    acc.z += __shfl_xor(acc.z, o);
    acc.w += __shfl_xor(acc.w, o);
  }
  if (grp == 0) {
    acc.x *= sinv; acc.y *= sinv; acc.z *= sinv; acc.w *= sinv;
    *(float4*)&out[(size_t)n * 64 + f4 * 4] = acc;
  }
}

// ---------------------------------------------------------------------------
extern "C" void kernel_launch(void* const* d_in, const int* in_sizes, int n_in,
                              void* d_out, int out_size, void* d_ws, size_t ws_size,
                              hipStream_t stream) {
  const float* x      = (const float*)d_in[0];
  const float* mask   = (const float*)d_in[1];
  const float* W0     = (const float*)d_in[2];
  const float* b0     = (const float*)d_in[3];
  const float* a_src0 = (const float*)d_in[4];
  const float* a_tgt0 = (const float*)d_in[5];
  const float* W1     = (const float*)d_in[6];
  const float* b1     = (const float*)d_in[7];
  const float* a_src1 = (const float*)d_in[8];
  const float* a_tgt1 = (const float*)d_in[9];
  float* out = (float*)d_out;

  // workspace layout (~22.3 MB)
  float* ws    = (float*)d_ws;
  float* proj0 = ws;                          // 4096*512 (dead after attn8h -> part aliases)
  float* h0    = proj0 + NNODES * 512;        // 4096*512
  float* proj1 = h0 + NNODES * 512;           // 4096*64
  float* ssrc0 = proj1 + NNODES * 64;         // 4096*8
  float* stgt0 = ssrc0 + NNODES * 8;          // 4096*8
  float* ssrc1 = stgt0 + NNODES * 8;          // 4096
  float* stgt1 = ssrc1 + NNODES;              // 4096
  int* deg  = (int*)(stgt1 + NNODES);         // 4096
  int* cols = deg + NNODES;                   // 4096*CAP
  float* part = proj0;                        // 4*4096*64 aliases proj0

  // D1: gemm0+scores0 (first 1024 blocks) + edge extraction (4096 blocks)
  phase1_kernel<<<NNODES + 1024, 256, 0, stream>>>(
      mask, deg, cols, x, W0, b0, a_src0, a_tgt0, proj0, ssrc0, stgt0);
  // D2: attn layer 0, head-half XCD split -> h0
  attn8h_kernel<<<NNODES * 2, 128, 0, stream>>>(proj0, ssrc0, stgt0, deg, cols, h0);
  // D3: gemm1 split-K x4 -> part
  gemm32x64_v2<<<dim3(NNODES / 32, 1, 4), 256, 0, stream>>>(
      h0, 512, W1, 64, part, 64);
  // D4: reduce + bias + scores1
  reduce_scores1_kernel<<<256, 256, 0, stream>>>(part, b1, a_src1, a_tgt1,
                                                 proj1, ssrc1, stgt1);
  // D5: attn layer 1
  attn1_kernel<<<NNODES, 64, 0, stream>>>(proj1, ssrc1, stgt1, deg, cols, out);
}

// Round 17
// 64.287 us; speedup vs baseline: 1.8903x; 1.0793x over previous
//
#include <hip/hip_runtime.h>
#include <hip/hip_bf16.h>

#define NNODES 4096
#define CAP 256

// Ledger: R11 grid.sync ~100us. R13 per-node W1 = 536MB. R15 node-amortize ->
// 2 blocks/CU stall. R16 best (69.4): head-half XCD split, gemm0-first.
// R17: linearity — Ph[m][h] = proj0_tile @ W1_slice computed INSIDE gemm0
// (hidden under mask scan); gather accumulates Ph directly into proj1 halves.
// Deletes gemm1 + reduce dispatches and the h0 round-trip.

// ---------------------------------------------------------------------------
// Phase 1: blocks [0,1024) = gemm0 tiles (+scores0 +Ph mini-GEMM), issued
// first to overlap under the mask scan; blocks [1024,5120) = edge rows.
// ---------------------------------------------------------------------------
__global__ __launch_bounds__(256) void phase1_kernel(
    const float* __restrict__ mask, int* __restrict__ deg, int* __restrict__ cols,
    const float* __restrict__ x, const float* __restrict__ W0,
    const float* __restrict__ b0, const float* __restrict__ a_src0,
    const float* __restrict__ a_tgt0, const float* __restrict__ W1,
    float* __restrict__ Ph, float* __restrict__ ssrc0,
    float* __restrict__ stgt0) {
  __shared__ float smem[6144];  // 24 KB
  const int t = threadIdx.x;
  if (blockIdx.x >= 1024) {
    const int n = blockIdx.x - 1024;
    const int lane = t & 63, wid = t >> 6;
    int* wsum = (int*)smem;
    const float4* row = (const float4*)(mask + (size_t)n * NNODES);
    float4 v[4];
    int cnt = 0;
#pragma unroll
    for (int j = 0; j < 4; ++j) {
      v[j] = row[t + 256 * j];  // coalesced
      cnt += (v[j].x == 0.0f) + (v[j].y == 0.0f) + (v[j].z == 0.0f) +
             (v[j].w == 0.0f);
    }
    int xs = cnt;
#pragma unroll
    for (int o = 1; o < 64; o <<= 1) {
      int y = __shfl_up(xs, o);
      if (lane >= o) xs += y;
    }
    if (lane == 63) wsum[wid] = xs;
    __syncthreads();
    int base = 0;
    for (int w = 0; w < wid; ++w) base += wsum[w];
    int off = base + xs - cnt;
    if (t == 0) {
      int total = wsum[0] + wsum[1] + wsum[2] + wsum[3];
      deg[n] = total < CAP ? total : CAP;
    }
    int* dst = cols + (size_t)n * CAP;
#pragma unroll
    for (int j = 0; j < 4; ++j) {
      const int c0 = (t + 256 * j) * 4;
      float fv[4] = {v[j].x, v[j].y, v[j].z, v[j].w};
#pragma unroll
      for (int k = 0; k < 4; ++k) {
        if (fv[k] == 0.0f) {
          if (off < CAP) dst[off] = c0 + k;
          ++off;
        }
      }
    }
  } else {
    // gemm0: 32x64 tile, K=128, BK=32 chunks, 2x4 reg blocking
    float(*As)[36] = (float(*)[36])smem;            // [0,1152)
    float(*Ws)[64] = (float(*)[64])(smem + 1152);   // [1152,3200)
    const int bx = blockIdx.x;
    const int brow = (bx & 127) * 32;
    const int head = bx >> 7;
    const int bcol = head * 64;
    const int tx = t & 15, ty = t >> 4;
    const int ar = t >> 3, ak = (t & 7) * 4;
    float acc[2][4] = {};
    for (int c = 0; c < 4; ++c) {
      const int k0 = c * 32;
      *(float4*)&As[ar][ak] =
          *(const float4*)&x[(size_t)(brow + ar) * 128 + k0 + ak];
#pragma unroll
      for (int q = 0; q < 2; ++q) {
        int i = t + q * 256;
        int k = i >> 4, c4 = (i & 15) * 4;
        *(float4*)&Ws[k][c4] =
            *(const float4*)&W0[(size_t)(k0 + k) * 512 + bcol + c4];
      }
      __syncthreads();
#pragma unroll 2
      for (int kk = 0; kk < 32; kk += 4) {
        float4 a0 = *(const float4*)&As[ty * 2 + 0][kk];
        float4 a1 = *(const float4*)&As[ty * 2 + 1][kk];
#pragma unroll
        for (int j = 0; j < 4; ++j) {
          float4 w = *(const float4*)&Ws[kk + j][tx * 4];
          float av0 = ((const float*)&a0)[j];
          float av1 = ((const float*)&a1)[j];
          acc[0][0] = fmaf(av0, w.x, acc[0][0]);
          acc[0][1] = fmaf(av0, w.y, acc[0][1]);
          acc[0][2] = fmaf(av0, w.z, acc[0][2]);
          acc[0][3] = fmaf(av0, w.w, acc[0][3]);
          acc[1][0] = fmaf(av1, w.x, acc[1][0]);
          acc[1][1] = fmaf(av1, w.y, acc[1][1]);
          acc[1][2] = fmaf(av1, w.z, acc[1][2]);
          acc[1][3] = fmaf(av1, w.w, acc[1][3]);
        }
      }
      __syncthreads();
    }
    // proj0 tile (+bias) -> LDS; fused scores0. Then Ph = tile @ W1slice.
    float(*tile)[64] = (float(*)[64])smem;          // [0,2048)
    float(*W1s)[64] = (float(*)[64])(smem + 2048);  // [2048,6144)
    const float4 bv = *(const float4*)&b0[bcol + tx * 4];
    const float4 as = *(const float4*)&a_src0[head * 64 + tx * 4];
    const float4 at = *(const float4*)&a_tgt0[head * 64 + tx * 4];
#pragma unroll
    for (int r = 0; r < 2; ++r) {
      float4 o;
      o.x = acc[r][0] + bv.x; o.y = acc[r][1] + bv.y;
      o.z = acc[r][2] + bv.z; o.w = acc[r][3] + bv.w;
      const int rowl = ty * 2 + r;
      *(float4*)&tile[rowl][tx * 4] = o;
      float ps = o.x * as.x + o.y * as.y + o.z * as.z + o.w * as.w;
      float pt = o.x * at.x + o.y * at.y + o.z * at.z + o.w * at.w;
#pragma unroll
      for (int m = 8; m; m >>= 1) {
        ps += __shfl_xor(ps, m);
        pt += __shfl_xor(pt, m);
      }
      if (tx == 0) {
        const size_t node = brow + rowl;
        ssrc0[node * 8 + head] = ps;
        stgt0[node * 8 + head] = pt;
      }
    }
    // stage W1 slice rows [head*64, head*64+64)
    for (int i = t; i < 1024; i += 256) {
      const int k = i >> 4, c4 = (i & 15) * 4;
      *(float4*)&W1s[k][c4] =
          *(const float4*)&W1[(size_t)(head * 64 + k) * 64 + c4];
    }
    __syncthreads();
    float acc2[2][4] = {};
#pragma unroll 4
    for (int k = 0; k < 64; ++k) {
      const float4 w4 = *(const float4*)&W1s[k][tx * 4];
      const float a0 = tile[ty * 2 + 0][k];
      const float a1 = tile[ty * 2 + 1][k];
      acc2[0][0] = fmaf(a0, w4.x, acc2[0][0]);
      acc2[0][1] = fmaf(a0, w4.y, acc2[0][1]);
      acc2[0][2] = fmaf(a0, w4.z, acc2[0][2]);
      acc2[0][3] = fmaf(a0, w4.w, acc2[0][3]);
      acc2[1][0] = fmaf(a1, w4.x, acc2[1][0]);
      acc2[1][1] = fmaf(a1, w4.y, acc2[1][1]);
      acc2[1][2] = fmaf(a1, w4.z, acc2[1][2]);
      acc2[1][3] = fmaf(a1, w4.w, acc2[1][3]);
    }
    // Ph layout [m][8 heads][64]
#pragma unroll
    for (int r = 0; r < 2; ++r) {
      float4 o;
      o.x = acc2[r][0]; o.y = acc2[r][1]; o.z = acc2[r][2]; o.w = acc2[r][3];
      *(float4*)&Ph[(size_t)(brow + ty * 2 + r) * 512 + head * 64 + tx * 4] = o;
    }
  }
}

// ---------------------------------------------------------------------------
// D2: layer-0 attention directly into proj1 halves via Ph.
// Block b: fh=(b&7)>>2 (head-half tied to XCD group), n=((b>>3)<<2)+(b&3).
// Per node: softmax over 4 local heads, normalize weights, gather
// Σ_e Σ_hl wn·Ph[m][hbase+hl][:], cross-head shfl reduce -> part[fh][n][64].
// ---------------------------------------------------------------------------
__global__ __launch_bounds__(128) void attnP_kernel(
    const float* __restrict__ Ph, const float* __restrict__ ssrc0,
    const float* __restrict__ stgt0, const int* __restrict__ deg,
    const int* __restrict__ cols, float* __restrict__ part) {
  const int b = blockIdx.x;
  const int fh = (b & 7) >> 2;
  const int n = ((b >> 3) << 2) + (b & 3);
  const int t = threadIdx.x;            // 128 threads = 2 waves
  const int lane = t & 63, wid = t >> 6;
  __shared__ int sm_[CAP];              // 1 KB
  __shared__ float sw[CAP * 5];         // 5 KB, stride 5
  __shared__ float sinv[4];
  __shared__ float4 buf[16];
  const int d = deg[n];
  for (int i = t; i < d; i += 128) sm_[i] = cols[(size_t)n * CAP + i];
  __syncthreads();
  const int hbase = fh * 4;
  for (int i = t; i < d * 4; i += 128) {
    const int e = i >> 2, h = i & 3;
    float s = ssrc0[n * 8 + hbase + h] + stgt0[sm_[e] * 8 + hbase + h];
    sw[e * 5 + h] = s >= 0.f ? s : 0.2f * s;
  }
  __syncthreads();
  for (int h = wid; h < 4; h += 2) {  // wave owns local heads h, h+2
    float mx = -1e30f;
    for (int e = lane; e < d; e += 64) mx = fmaxf(mx, sw[e * 5 + h]);
#pragma unroll
    for (int o = 32; o; o >>= 1) mx = fmaxf(mx, __shfl_xor(mx, o));
    float sum = 0.f;
    for (int e = lane; e < d; e += 64) {
      float w = __expf(sw[e * 5 + h] - mx);
      sw[e * 5 + h] = w;
      sum += w;
    }
#pragma unroll
    for (int o = 32; o; o >>= 1) sum += __shfl_xor(sum, o);
    if (lane == 0) sinv[h] = 1.0f / sum;
  }
  __syncthreads();
  // normalize weights in place
  for (int i = t; i < d * 4; i += 128) {
    const int e = i >> 2, h = i & 3;
    sw[e * 5 + h] *= sinv[h];
  }
  __syncthreads();
  // gather: lane covers (hl=lane>>4, f=lane&15); contiguous 1KB per edge-half
  const int grp = t >> 6;               // 2-way edge split
  const int hl = lane >> 4;
  float4 acc = make_float4(0.f, 0.f, 0.f, 0.f);
  for (int e = grp; e < d; e += 2) {
    const float w = sw[e * 5 + hl];
    const float4 pv =
        *(const float4*)&Ph[(size_t)sm_[e] * 512 + fh * 256 + lane * 4];
    acc.x = fmaf(w, pv.x, acc.x);
    acc.y = fmaf(w, pv.y, acc.y);
    acc.z = fmaf(w, pv.z, acc.z);
    acc.w = fmaf(w, pv.w, acc.w);
  }
  // cross-head reduce within wave: lanes f, f+16, f+32, f+48 sum
#pragma unroll
  for (int o = 16; o <= 32; o <<= 1) {
    acc.x += __shfl_xor(acc.x, o);
    acc.y += __shfl_xor(acc.y, o);
    acc.z += __shfl_xor(acc.z, o);
    acc.w += __shfl_xor(acc.w, o);
  }
  if (grp == 1 && lane < 16) buf[lane] = acc;
  __syncthreads();
  if (grp == 0 && lane < 16) {
    const float4 o2 = buf[lane];
    float4 o;
    o.x = acc.x + o2.x; o.y = acc.y + o2.y;
    o.z = acc.z + o2.z; o.w = acc.w + o2.w;
    *(float4*)&part[(size_t)fh * (NNODES * 64) + (size_t)n * 64 + lane * 4] = o;
  }
}

// ---------------------------------------------------------------------------
// D3: proj1 = part0 + part1 + b1; fused scores1 (16-lane shfl reduce).
// ---------------------------------------------------------------------------
__global__ __launch_bounds__(256) void finalize_scores1_kernel(
    const float* __restrict__ part, const float* __restrict__ bias,
    const float* __restrict__ a_src1, const float* __restrict__ a_tgt1,
    float* __restrict__ proj1, float* __restrict__ ssrc1,
    float* __restrict__ stgt1) {
  const int i = blockIdx.x * 256 + threadIdx.x;  // float4 idx, 65536 total
  const float4* p = (const float4*)part;
  float4 a = p[i], b = p[i + 65536];
  const int f4 = i & 15;
  const float4 bb = *(const float4*)&bias[f4 * 4];
  float4 r;
  r.x = a.x + b.x + bb.x;
  r.y = a.y + b.y + bb.y;
  r.z = a.z + b.z + bb.z;
  r.w = a.w + b.w + bb.w;
  ((float4*)proj1)[i] = r;
  const float4 as = *(const float4*)&a_src1[f4 * 4];
  const float4 at = *(const float4*)&a_tgt1[f4 * 4];
  float ps = r.x * as.x + r.y * as.y + r.z * as.z + r.w * as.w;
  float pt = r.x * at.x + r.y * at.y + r.z * at.z + r.w * at.w;
#pragma unroll
  for (int m = 8; m; m >>= 1) {
    ps += __shfl_xor(ps, m);
    pt += __shfl_xor(pt, m);
  }
  if (f4 == 0) {
    const int node = i >> 4;
    ssrc1[node] = ps;
    stgt1[node] = pt;
  }
}

// ---------------------------------------------------------------------------
// D4: attn layer 1 (H=1): one wave per node; float4 gather, 4-way edge split.
// ---------------------------------------------------------------------------
__global__ void attn1_kernel(
    const float* __restrict__ proj, const float* __restrict__ s_src,
    const float* __restrict__ s_tgt, const int* __restrict__ deg,
    const int* __restrict__ cols, float* __restrict__ out) {
  const int n = blockIdx.x;
  const int tid = threadIdx.x;  // 64 threads = 1 wave
  __shared__ int sm_[CAP];
  __shared__ float sw[CAP];
  const int d = deg[n];
  for (int i = tid; i < d; i += 64) sm_[i] = cols[(size_t)n * CAP + i];
  __syncthreads();
  const float ssn = s_src[n];
  for (int i = tid; i < d; i += 64) {
    float s = ssn + s_tgt[sm_[i]];
    sw[i] = s >= 0.f ? s : 0.2f * s;
  }
  __syncthreads();
  float mx = -1e30f;
  for (int e = tid; e < d; e += 64) mx = fmaxf(mx, sw[e]);
#pragma unroll
  for (int o = 32; o; o >>= 1) mx = fmaxf(mx, __shfl_xor(mx, o));
  float sum = 0.f;
  for (int e = tid; e < d; e += 64) {
    float w = __expf(sw[e] - mx);
    sw[e] = w;
    sum += w;
  }
#pragma unroll
  for (int o = 32; o; o >>= 1) sum += __shfl_xor(sum, o);
  const float sinv = 1.0f / sum;
  __syncthreads();
  const int f4 = tid & 15, grp = tid >> 4;  // 16 float4 outputs, 4-way edges
  float4 acc = make_float4(0.f, 0.f, 0.f, 0.f);
  for (int e = grp; e < d; e += 4) {
    const float w = sw[e];
    const float4 pv = *(const float4*)&proj[(size_t)sm_[e] * 64 + f4 * 4];
    acc.x = fmaf(w, pv.x, acc.x);
    acc.y = fmaf(w, pv.y, acc.y);
    acc.z = fmaf(w, pv.z, acc.z);
    acc.w = fmaf(w, pv.w, acc.w);
  }
#pragma unroll
  for (int o = 16; o <= 32; o <<= 1) {
    acc.x += __shfl_xor(acc.x, o);
    acc.y += __shfl_xor(acc.y, o);
    acc.z += __shfl_xor(acc.z, o);
    acc.w += __shfl_xor(acc.w, o);
  }
  if (grp == 0) {
    acc.x *= sinv; acc.y *= sinv; acc.z *= sinv; acc.w *= sinv;
    *(float4*)&out[(size_t)n * 64 + f4 * 4] = acc;
  }
}

// ---------------------------------------------------------------------------
extern "C" void kernel_launch(void* const* d_in, const int* in_sizes, int n_in,
                              void* d_out, int out_size, void* d_ws, size_t ws_size,
                              hipStream_t stream) {
  const float* x      = (const float*)d_in[0];
  const float* mask   = (const float*)d_in[1];
  const float* W0     = (const float*)d_in[2];
  const float* b0     = (const float*)d_in[3];
  const float* a_src0 = (const float*)d_in[4];
  const float* a_tgt0 = (const float*)d_in[5];
  const float* W1     = (const float*)d_in[6];
  const float* b1     = (const float*)d_in[7];
  const float* a_src1 = (const float*)d_in[8];
  const float* a_tgt1 = (const float*)d_in[9];
  float* out = (float*)d_out;

  // workspace layout (~16.6 MB)
  float* ws    = (float*)d_ws;
  float* Ph    = ws;                          // 4096*512 (8 MB)
  float* part  = Ph + NNODES * 512;           // 2*4096*64 (2 MB)
  float* proj1 = part + 2 * NNODES * 64;      // 4096*64
  float* ssrc0 = proj1 + NNODES * 64;         // 4096*8
  float* stgt0 = ssrc0 + NNODES * 8;          // 4096*8
  float* ssrc1 = stgt0 + NNODES * 8;          // 4096
  float* stgt1 = ssrc1 + NNODES;              // 4096
  int* deg  = (int*)(stgt1 + NNODES);         // 4096
  int* cols = deg + NNODES;                   // 4096*CAP

  // D1: gemm0+scores0+Ph (first 1024 blocks) + edge extraction (4096 blocks)
  phase1_kernel<<<NNODES + 1024, 256, 0, stream>>>(
      mask, deg, cols, x, W0, b0, a_src0, a_tgt0, W1, Ph, ssrc0, stgt0);
  // D2: layer-0 attention -> proj1 halves (head-half XCD split)
  attnP_kernel<<<NNODES * 2, 128, 0, stream>>>(Ph, ssrc0, stgt0, deg, cols, part);
  // D3: proj1 = part0+part1+b1, scores1
  finalize_scores1_kernel<<<256, 256, 0, stream>>>(part, b1, a_src1, a_tgt1,
                                                   proj1, ssrc1, stgt1);
  // D4: attn layer 1
  attn1_kernel<<<NNODES, 64, 0, stream>>>(proj1, ssrc1, stgt1, deg, cols, out);
}

// Round 18
// 59.478 us; speedup vs baseline: 2.0431x; 1.0808x over previous
//
#include <hip/hip_runtime.h>
#include <hip/hip_bf16.h>

#define NNODES 4096
#define CAP 256

// Ledger: R11 grid.sync ~100us. R13 per-node W1 = 536MB. R15 node-amortize ->
// 2 blocks/CU stall. R16: head-half XCD split (69.4). R17: Ph linearity
// restructure (64.3). R18: u16 cols (L2 footprint), sinv folded into acc,
// ILP-2 gather on the now-L2-resident working set.

// ---------------------------------------------------------------------------
// Phase 1: blocks [0,1024) = gemm0 tiles (+scores0 +Ph mini-GEMM), issued
// first to overlap under the mask scan; blocks [1024,5120) = edge rows.
// ---------------------------------------------------------------------------
__global__ __launch_bounds__(256) void phase1_kernel(
    const float* __restrict__ mask, int* __restrict__ deg,
    unsigned short* __restrict__ cols, const float* __restrict__ x,
    const float* __restrict__ W0, const float* __restrict__ b0,
    const float* __restrict__ a_src0, const float* __restrict__ a_tgt0,
    const float* __restrict__ W1, float* __restrict__ Ph,
    float* __restrict__ ssrc0, float* __restrict__ stgt0) {
  __shared__ float smem[6144];  // 24 KB
  const int t = threadIdx.x;
  if (blockIdx.x >= 1024) {
    const int n = blockIdx.x - 1024;
    const int lane = t & 63, wid = t >> 6;
    int* wsum = (int*)smem;
    const float4* row = (const float4*)(mask + (size_t)n * NNODES);
    float4 v[4];
    int cnt = 0;
#pragma unroll
    for (int j = 0; j < 4; ++j) {
      v[j] = row[t + 256 * j];  // coalesced
      cnt += (v[j].x == 0.0f) + (v[j].y == 0.0f) + (v[j].z == 0.0f) +
             (v[j].w == 0.0f);
    }
    int xs = cnt;
#pragma unroll
    for (int o = 1; o < 64; o <<= 1) {
      int y = __shfl_up(xs, o);
      if (lane >= o) xs += y;
    }
    if (lane == 63) wsum[wid] = xs;
    __syncthreads();
    int base = 0;
    for (int w = 0; w < wid; ++w) base += wsum[w];
    int off = base + xs - cnt;
    if (t == 0) {
      int total = wsum[0] + wsum[1] + wsum[2] + wsum[3];
      deg[n] = total < CAP ? total : CAP;
    }
    unsigned short* dst = cols + (size_t)n * CAP;
#pragma unroll
    for (int j = 0; j < 4; ++j) {
      const int c0 = (t + 256 * j) * 4;
      float fv[4] = {v[j].x, v[j].y, v[j].z, v[j].w};
#pragma unroll
      for (int k = 0; k < 4; ++k) {
        if (fv[k] == 0.0f) {
          if (off < CAP) dst[off] = (unsigned short)(c0 + k);
          ++off;
        }
      }
    }
  } else {
    // gemm0: 32x64 tile, K=128, BK=32 chunks, 2x4 reg blocking
    float(*As)[36] = (float(*)[36])smem;            // [0,1152)
    float(*Ws)[64] = (float(*)[64])(smem + 1152);   // [1152,3200)
    const int bx = blockIdx.x;
    const int brow = (bx & 127) * 32;
    const int head = bx >> 7;
    const int bcol = head * 64;
    const int tx = t & 15, ty = t >> 4;
    const int ar = t >> 3, ak = (t & 7) * 4;
    float acc[2][4] = {};
    for (int c = 0; c < 4; ++c) {
      const int k0 = c * 32;
      *(float4*)&As[ar][ak] =
          *(const float4*)&x[(size_t)(brow + ar) * 128 + k0 + ak];
#pragma unroll
      for (int q = 0; q < 2; ++q) {
        int i = t + q * 256;
        int k = i >> 4, c4 = (i & 15) * 4;
        *(float4*)&Ws[k][c4] =
            *(const float4*)&W0[(size_t)(k0 + k) * 512 + bcol + c4];
      }
      __syncthreads();
#pragma unroll 2
      for (int kk = 0; kk < 32; kk += 4) {
        float4 a0 = *(const float4*)&As[ty * 2 + 0][kk];
        float4 a1 = *(const float4*)&As[ty * 2 + 1][kk];
#pragma unroll
        for (int j = 0; j < 4; ++j) {
          float4 w = *(const float4*)&Ws[kk + j][tx * 4];
          float av0 = ((const float*)&a0)[j];
          float av1 = ((const float*)&a1)[j];
          acc[0][0] = fmaf(av0, w.x, acc[0][0]);
          acc[0][1] = fmaf(av0, w.y, acc[0][1]);
          acc[0][2] = fmaf(av0, w.z, acc[0][2]);
          acc[0][3] = fmaf(av0, w.w, acc[0][3]);
          acc[1][0] = fmaf(av1, w.x, acc[1][0]);
          acc[1][1] = fmaf(av1, w.y, acc[1][1]);
          acc[1][2] = fmaf(av1, w.z, acc[1][2]);
          acc[1][3] = fmaf(av1, w.w, acc[1][3]);
        }
      }
      __syncthreads();
    }
    // proj0 tile (+bias) -> LDS; fused scores0. Then Ph = tile @ W1slice.
    float(*tile)[64] = (float(*)[64])smem;          // [0,2048)
    float(*W1s)[64] = (float(*)[64])(smem + 2048);  // [2048,6144)
    const float4 bv = *(const float4*)&b0[bcol + tx * 4];
    const float4 as = *(const float4*)&a_src0[head * 64 + tx * 4];
    const float4 at = *(const float4*)&a_tgt0[head * 64 + tx * 4];
#pragma unroll
    for (int r = 0; r < 2; ++r) {
      float4 o;
      o.x = acc[r][0] + bv.x; o.y = acc[r][1] + bv.y;
      o.z = acc[r][2] + bv.z; o.w = acc[r][3] + bv.w;
      const int rowl = ty * 2 + r;
      *(float4*)&tile[rowl][tx * 4] = o;
      float ps = o.x * as.x + o.y * as.y + o.z * as.z + o.w * as.w;
      float pt = o.x * at.x + o.y * at.y + o.z * at.z + o.w * at.w;
#pragma unroll
      for (int m = 8; m; m >>= 1) {
        ps += __shfl_xor(ps, m);
        pt += __shfl_xor(pt, m);
      }
      if (tx == 0) {
        const size_t node = brow + rowl;
        ssrc0[node * 8 + head] = ps;
        stgt0[node * 8 + head] = pt;
      }
    }
    // stage W1 slice rows [head*64, head*64+64)
    for (int i = t; i < 1024; i += 256) {
      const int k = i >> 4, c4 = (i & 15) * 4;
      *(float4*)&W1s[k][c4] =
          *(const float4*)&W1[(size_t)(head * 64 + k) * 64 + c4];
    }
    __syncthreads();
    float acc2[2][4] = {};
#pragma unroll 4
    for (int k = 0; k < 64; ++k) {
      const float4 w4 = *(const float4*)&W1s[k][tx * 4];
      const float a0 = tile[ty * 2 + 0][k];
      const float a1 = tile[ty * 2 + 1][k];
      acc2[0][0] = fmaf(a0, w4.x, acc2[0][0]);
      acc2[0][1] = fmaf(a0, w4.y, acc2[0][1]);
      acc2[0][2] = fmaf(a0, w4.z, acc2[0][2]);
      acc2[0][3] = fmaf(a0, w4.w, acc2[0][3]);
      acc2[1][0] = fmaf(a1, w4.x, acc2[1][0]);
      acc2[1][1] = fmaf(a1, w4.y, acc2[1][1]);
      acc2[1][2] = fmaf(a1, w4.z, acc2[1][2]);
      acc2[1][3] = fmaf(a1, w4.w, acc2[1][3]);
    }
    // Ph layout [m][8 heads][64]
#pragma unroll
    for (int r = 0; r < 2; ++r) {
      float4 o;
      o.x = acc2[r][0]; o.y = acc2[r][1]; o.z = acc2[r][2]; o.w = acc2[r][3];
      *(float4*)&Ph[(size_t)(brow + ty * 2 + r) * 512 + head * 64 + tx * 4] = o;
    }
  }
}

// ---------------------------------------------------------------------------
// D2: layer-0 attention directly into proj1 halves via Ph.
// Block b: fh=(b&7)>>2 (head-half tied to XCD group), n=((b>>3)<<2)+(b&3).
// sinv folded into accumulators (no normalize pass); ILP-2 gather.
// ---------------------------------------------------------------------------
__global__ __launch_bounds__(128) void attnP_kernel(
    const float* __restrict__ Ph, const float* __restrict__ ssrc0,
    const float* __restrict__ stgt0, const int* __restrict__ deg,
    const unsigned short* __restrict__ cols, float* __restrict__ part) {
  const int b = blockIdx.x;
  const int fh = (b & 7) >> 2;
  const int n = ((b >> 3) << 2) + (b & 3);
  const int t = threadIdx.x;            // 128 threads = 2 waves
  const int lane = t & 63, wid = t >> 6;
  __shared__ int sm_[CAP];              // 1 KB
  __shared__ float sw[CAP * 5];         // 5 KB, stride 5
  __shared__ float sinv[4];
  __shared__ float4 buf[16];
  const int d = deg[n];
  for (int i = t; i < d; i += 128) sm_[i] = cols[(size_t)n * CAP + i];
  __syncthreads();
  const int hbase = fh * 4;
  for (int i = t; i < d * 4; i += 128) {
    const int e = i >> 2, h = i & 3;
    float s = ssrc0[n * 8 + hbase + h] + stgt0[sm_[e] * 8 + hbase + h];
    sw[e * 5 + h] = s >= 0.f ? s : 0.2f * s;
  }
  __syncthreads();
  for (int h = wid; h < 4; h += 2) {  // wave owns local heads h, h+2
    float mx = -1e30f;
    for (int e = lane; e < d; e += 64) mx = fmaxf(mx, sw[e * 5 + h]);
#pragma unroll
    for (int o = 32; o; o >>= 1) mx = fmaxf(mx, __shfl_xor(mx, o));
    float sum = 0.f;
    for (int e = lane; e < d; e += 64) {
      float w = __expf(sw[e * 5 + h] - mx);
      sw[e * 5 + h] = w;
      sum += w;
    }
#pragma unroll
    for (int o = 32; o; o >>= 1) sum += __shfl_xor(sum, o);
    if (lane == 0) sinv[h] = 1.0f / sum;
  }
  __syncthreads();
  // gather: lane covers (hl=lane>>4, f=lane&15); 1KB contiguous per edge-half.
  // ILP-2: edges e, e+2 within this grp (L2-resident -> latency hiding pays).
  const int grp = t >> 6;               // 2-way edge split
  const int hl = lane >> 4;
  float4 a0 = make_float4(0.f, 0.f, 0.f, 0.f), a1 = a0;
  int e = grp;
  for (; e + 2 < d; e += 4) {
    const int m0 = sm_[e], m1 = sm_[e + 2];
    const float w0 = sw[e * 5 + hl], w1 = sw[(e + 2) * 5 + hl];
    const float4 p0 =
        *(const float4*)&Ph[(size_t)m0 * 512 + fh * 256 + lane * 4];
    const float4 p1 =
        *(const float4*)&Ph[(size_t)m1 * 512 + fh * 256 + lane * 4];
    a0.x = fmaf(w0, p0.x, a0.x); a0.y = fmaf(w0, p0.y, a0.y);
    a0.z = fmaf(w0, p0.z, a0.z); a0.w = fmaf(w0, p0.w, a0.w);
    a1.x = fmaf(w1, p1.x, a1.x); a1.y = fmaf(w1, p1.y, a1.y);
    a1.z = fmaf(w1, p1.z, a1.z); a1.w = fmaf(w1, p1.w, a1.w);
  }
  for (; e < d; e += 2) {
    const float w = sw[e * 5 + hl];
    const float4 pv =
        *(const float4*)&Ph[(size_t)sm_[e] * 512 + fh * 256 + lane * 4];
    a0.x = fmaf(w, pv.x, a0.x); a0.y = fmaf(w, pv.y, a0.y);
    a0.z = fmaf(w, pv.z, a0.z); a0.w = fmaf(w, pv.w, a0.w);
  }
  const float s = sinv[hl];  // fold normalization into the accumulator
  float4 acc;
  acc.x = (a0.x + a1.x) * s;
  acc.y = (a0.y + a1.y) * s;
  acc.z = (a0.z + a1.z) * s;
  acc.w = (a0.w + a1.w) * s;
  // cross-head reduce within wave: lanes f, f+16, f+32, f+48 sum
#pragma unroll
  for (int o = 16; o <= 32; o <<= 1) {
    acc.x += __shfl_xor(acc.x, o);
    acc.y += __shfl_xor(acc.y, o);
    acc.z += __shfl_xor(acc.z, o);
    acc.w += __shfl_xor(acc.w, o);
  }
  if (grp == 1 && lane < 16) buf[lane] = acc;
  __syncthreads();
  if (grp == 0 && lane < 16) {
    const float4 o2 = buf[lane];
    float4 o;
    o.x = acc.x + o2.x; o.y = acc.y + o2.y;
    o.z = acc.z + o2.z; o.w = acc.w + o2.w;
    *(float4*)&part[(size_t)fh * (NNODES * 64) + (size_t)n * 64 + lane * 4] = o;
  }
}

// ---------------------------------------------------------------------------
// D3: proj1 = part0 + part1 + b1; fused scores1 (16-lane shfl reduce).
// ---------------------------------------------------------------------------
__global__ __launch_bounds__(256) void finalize_scores1_kernel(
    const float* __restrict__ part, const float* __restrict__ bias,
    const float* __restrict__ a_src1, const float* __restrict__ a_tgt1,
    float* __restrict__ proj1, float* __restrict__ ssrc1,
    float* __restrict__ stgt1) {
  const int i = blockIdx.x * 256 + threadIdx.x;  // float4 idx, 65536 total
  const float4* p = (const float4*)part;
  float4 a = p[i], b = p[i + 65536];
  const int f4 = i & 15;
  const float4 bb = *(const float4*)&bias[f4 * 4];
  float4 r;
  r.x = a.x + b.x + bb.x;
  r.y = a.y + b.y + bb.y;
  r.z = a.z + b.z + bb.z;
  r.w = a.w + b.w + bb.w;
  ((float4*)proj1)[i] = r;
  const float4 as = *(const float4*)&a_src1[f4 * 4];
  const float4 at = *(const float4*)&a_tgt1[f4 * 4];
  float ps = r.x * as.x + r.y * as.y + r.z * as.z + r.w * as.w;
  float pt = r.x * at.x + r.y * at.y + r.z * at.z + r.w * at.w;
#pragma unroll
  for (int m = 8; m; m >>= 1) {
    ps += __shfl_xor(ps, m);
    pt += __shfl_xor(pt, m);
  }
  if (f4 == 0) {
    const int node = i >> 4;
    ssrc1[node] = ps;
    stgt1[node] = pt;
  }
}

// ---------------------------------------------------------------------------
// D4: attn layer 1 (H=1): one wave per node; float4 gather, 4-way edge split.
// ---------------------------------------------------------------------------
__global__ void attn1_kernel(
    const float* __restrict__ proj, const float* __restrict__ s_src,
    const float* __restrict__ s_tgt, const int* __restrict__ deg,
    const unsigned short* __restrict__ cols, float* __restrict__ out) {
  const int n = blockIdx.x;
  const int tid = threadIdx.x;  // 64 threads = 1 wave
  __shared__ int sm_[CAP];
  __shared__ float sw[CAP];
  const int d = deg[n];
  for (int i = tid; i < d; i += 64) sm_[i] = cols[(size_t)n * CAP + i];
  __syncthreads();
  const float ssn = s_src[n];
  for (int i = tid; i < d; i += 64) {
    float s = ssn + s_tgt[sm_[i]];
    sw[i] = s >= 0.f ? s : 0.2f * s;
  }
  __syncthreads();
  float mx = -1e30f;
  for (int e = tid; e < d; e += 64) mx = fmaxf(mx, sw[e]);
#pragma unroll
  for (int o = 32; o; o >>= 1) mx = fmaxf(mx, __shfl_xor(mx, o));
  float sum = 0.f;
  for (int e = tid; e < d; e += 64) {
    float w = __expf(sw[e] - mx);
    sw[e] = w;
    sum += w;
  }
#pragma unroll
  for (int o = 32; o; o >>= 1) sum += __shfl_xor(sum, o);
  const float sinv = 1.0f / sum;
  __syncthreads();
  const int f4 = tid & 15, grp = tid >> 4;  // 16 float4 outputs, 4-way edges
  float4 acc = make_float4(0.f, 0.f, 0.f, 0.f);
  for (int e = grp; e < d; e += 4) {
    const float w = sw[e];
    const float4 pv = *(const float4*)&proj[(size_t)sm_[e] * 64 + f4 * 4];
    acc.x = fmaf(w, pv.x, acc.x);
    acc.y = fmaf(w, pv.y, acc.y);
    acc.z = fmaf(w, pv.z, acc.z);
    acc.w = fmaf(w, pv.w, acc.w);
  }
#pragma unroll
  for (int o = 16; o <= 32; o <<= 1) {
    acc.x += __shfl_xor(acc.x, o);
    acc.y += __shfl_xor(acc.y, o);
    acc.z += __shfl_xor(acc.z, o);
    acc.w += __shfl_xor(acc.w, o);
  }
  if (grp == 0) {
    acc.x *= sinv; acc.y *= sinv; acc.z *= sinv; acc.w *= sinv;
    *(float4*)&out[(size_t)n * 64 + f4 * 4] = acc;
  }
}

// ---------------------------------------------------------------------------
extern "C" void kernel_launch(void* const* d_in, const int* in_sizes, int n_in,
                              void* d_out, int out_size, void* d_ws, size_t ws_size,
                              hipStream_t stream) {
  const float* x      = (const float*)d_in[0];
  const float* mask   = (const float*)d_in[1];
  const float* W0     = (const float*)d_in[2];
  const float* b0     = (const float*)d_in[3];
  const float* a_src0 = (const float*)d_in[4];
  const float* a_tgt0 = (const float*)d_in[5];
  const float* W1     = (const float*)d_in[6];
  const float* b1     = (const float*)d_in[7];
  const float* a_src1 = (const float*)d_in[8];
  const float* a_tgt1 = (const float*)d_in[9];
  float* out = (float*)d_out;

  // workspace layout (~14.6 MB)
  float* ws    = (float*)d_ws;
  float* Ph    = ws;                          // 4096*512 (8 MB)
  float* part  = Ph + NNODES * 512;           // 2*4096*64 (2 MB)
  float* proj1 = part + 2 * NNODES * 64;      // 4096*64
  float* ssrc0 = proj1 + NNODES * 64;         // 4096*8
  float* stgt0 = ssrc0 + NNODES * 8;          // 4096*8
  float* ssrc1 = stgt0 + NNODES * 8;          // 4096
  float* stgt1 = ssrc1 + NNODES;              // 4096
  int* deg = (int*)(stgt1 + NNODES);          // 4096
  unsigned short* cols = (unsigned short*)(deg + NNODES);  // 4096*CAP u16 (2MB)

  // D1: gemm0+scores0+Ph (first 1024 blocks) + edge extraction (4096 blocks)
  phase1_kernel<<<NNODES + 1024, 256, 0, stream>>>(
      mask, deg, cols, x, W0, b0, a_src0, a_tgt0, W1, Ph, ssrc0, stgt0);
  // D2: layer-0 attention -> proj1 halves (head-half XCD split)
  attnP_kernel<<<NNODES * 2, 128, 0, stream>>>(Ph, ssrc0, stgt0, deg, cols, part);
  // D3: proj1 = part0+part1+b1, scores1
  finalize_scores1_kernel<<<256, 256, 0, stream>>>(part, b1, a_src1, a_tgt1,
                                                   proj1, ssrc1, stgt1);
  // D4: attn layer 1
  attn1_kernel<<<NNODES, 64, 0, stream>>>(proj1, ssrc1, stgt1, deg, cols, out);
}

// Round 19
// 56.805 us; speedup vs baseline: 2.1393x; 1.0471x over previous
//
#include <hip/hip_runtime.h>
#include <hip/hip_bf16.h>

#define NNODES 4096
#define CAP 256

// Ledger: R11 grid.sync ~100us. R13 per-node W1 = 536MB. R15 node-amortize
// stall. R16 head-half XCD split (69.4). R17 Ph linearity (64.3). R18 u16
// cols + folded sinv + ILP2 (59.5). R19: head-QUARTER split -> per-XCD
// resident set 3.3MB < 4MB L2 (half split was exactly 4MB -> thrash).

// ---------------------------------------------------------------------------
// Phase 1: blocks [0,1024) = gemm0 tiles (+scores0 +Ph mini-GEMM), issued
// first to overlap under the mask scan; blocks [1024,5120) = edge rows.
// ---------------------------------------------------------------------------
__global__ __launch_bounds__(256) void phase1_kernel(
    const float* __restrict__ mask, int* __restrict__ deg,
    unsigned short* __restrict__ cols, const float* __restrict__ x,
    const float* __restrict__ W0, const float* __restrict__ b0,
    const float* __restrict__ a_src0, const float* __restrict__ a_tgt0,
    const float* __restrict__ W1, float* __restrict__ Ph,
    float* __restrict__ ssrc0, float* __restrict__ stgt0) {
  __shared__ float smem[6144];  // 24 KB
  const int t = threadIdx.x;
  if (blockIdx.x >= 1024) {
    const int n = blockIdx.x - 1024;
    const int lane = t & 63, wid = t >> 6;
    int* wsum = (int*)smem;
    const float4* row = (const float4*)(mask + (size_t)n * NNODES);
    float4 v[4];
    int cnt = 0;
#pragma unroll
    for (int j = 0; j < 4; ++j) {
      v[j] = row[t + 256 * j];  // coalesced
      cnt += (v[j].x == 0.0f) + (v[j].y == 0.0f) + (v[j].z == 0.0f) +
             (v[j].w == 0.0f);
    }
    int xs = cnt;
#pragma unroll
    for (int o = 1; o < 64; o <<= 1) {
      int y = __shfl_up(xs, o);
      if (lane >= o) xs += y;
    }
    if (lane == 63) wsum[wid] = xs;
    __syncthreads();
    int base = 0;
    for (int w = 0; w < wid; ++w) base += wsum[w];
    int off = base + xs - cnt;
    if (t == 0) {
      int total = wsum[0] + wsum[1] + wsum[2] + wsum[3];
      deg[n] = total < CAP ? total : CAP;
    }
    unsigned short* dst = cols + (size_t)n * CAP;
#pragma unroll
    for (int j = 0; j < 4; ++j) {
      const int c0 = (t + 256 * j) * 4;
      float fv[4] = {v[j].x, v[j].y, v[j].z, v[j].w};
#pragma unroll
      for (int k = 0; k < 4; ++k) {
        if (fv[k] == 0.0f) {
          if (off < CAP) dst[off] = (unsigned short)(c0 + k);
          ++off;
        }
      }
    }
  } else {
    // gemm0: 32x64 tile, K=128, BK=32 chunks, 2x4 reg blocking
    float(*As)[36] = (float(*)[36])smem;            // [0,1152)
    float(*Ws)[64] = (float(*)[64])(smem + 1152);   // [1152,3200)
    const int bx = blockIdx.x;
    const int brow = (bx & 127) * 32;
    const int head = bx >> 7;
    const int bcol = head * 64;
    const int tx = t & 15, ty = t >> 4;
    const int ar = t >> 3, ak = (t & 7) * 4;
    float acc[2][4] = {};
    for (int c = 0; c < 4; ++c) {
      const int k0 = c * 32;
      *(float4*)&As[ar][ak] =
          *(const float4*)&x[(size_t)(brow + ar) * 128 + k0 + ak];
#pragma unroll
      for (int q = 0; q < 2; ++q) {
        int i = t + q * 256;
        int k = i >> 4, c4 = (i & 15) * 4;
        *(float4*)&Ws[k][c4] =
            *(const float4*)&W0[(size_t)(k0 + k) * 512 + bcol + c4];
      }
      __syncthreads();
#pragma unroll 2
      for (int kk = 0; kk < 32; kk += 4) {
        float4 a0 = *(const float4*)&As[ty * 2 + 0][kk];
        float4 a1 = *(const float4*)&As[ty * 2 + 1][kk];
#pragma unroll
        for (int j = 0; j < 4; ++j) {
          float4 w = *(const float4*)&Ws[kk + j][tx * 4];
          float av0 = ((const float*)&a0)[j];
          float av1 = ((const float*)&a1)[j];
          acc[0][0] = fmaf(av0, w.x, acc[0][0]);
          acc[0][1] = fmaf(av0, w.y, acc[0][1]);
          acc[0][2] = fmaf(av0, w.z, acc[0][2]);
          acc[0][3] = fmaf(av0, w.w, acc[0][3]);
          acc[1][0] = fmaf(av1, w.x, acc[1][0]);
          acc[1][1] = fmaf(av1, w.y, acc[1][1]);
          acc[1][2] = fmaf(av1, w.z, acc[1][2]);
          acc[1][3] = fmaf(av1, w.w, acc[1][3]);
        }
      }
      __syncthreads();
    }
    // proj0 tile (+bias) -> LDS; fused scores0. Then Ph = tile @ W1slice.
    float(*tile)[64] = (float(*)[64])smem;          // [0,2048)
    float(*W1s)[64] = (float(*)[64])(smem + 2048);  // [2048,6144)
    const float4 bv = *(const float4*)&b0[bcol + tx * 4];
    const float4 as = *(const float4*)&a_src0[head * 64 + tx * 4];
    const float4 at = *(const float4*)&a_tgt0[head * 64 + tx * 4];
#pragma unroll
    for (int r = 0; r < 2; ++r) {
      float4 o;
      o.x = acc[r][0] + bv.x; o.y = acc[r][1] + bv.y;
      o.z = acc[r][2] + bv.z; o.w = acc[r][3] + bv.w;
      const int rowl = ty * 2 + r;
      *(float4*)&tile[rowl][tx * 4] = o;
      float ps = o.x * as.x + o.y * as.y + o.z * as.z + o.w * as.w;
      float pt = o.x * at.x + o.y * at.y + o.z * at.z + o.w * at.w;
#pragma unroll
      for (int m = 8; m; m >>= 1) {
        ps += __shfl_xor(ps, m);
        pt += __shfl_xor(pt, m);
      }
      if (tx == 0) {
        const size_t node = brow + rowl;
        ssrc0[node * 8 + head] = ps;
        stgt0[node * 8 + head] = pt;
      }
    }
    // stage W1 slice rows [head*64, head*64+64)
    for (int i = t; i < 1024; i += 256) {
      const int k = i >> 4, c4 = (i & 15) * 4;
      *(float4*)&W1s[k][c4] =
          *(const float4*)&W1[(size_t)(head * 64 + k) * 64 + c4];
    }
    __syncthreads();
    float acc2[2][4] = {};
#pragma unroll 4
    for (int k = 0; k < 64; ++k) {
      const float4 w4 = *(const float4*)&W1s[k][tx * 4];
      const float a0 = tile[ty * 2 + 0][k];
      const float a1 = tile[ty * 2 + 1][k];
      acc2[0][0] = fmaf(a0, w4.x, acc2[0][0]);
      acc2[0][1] = fmaf(a0, w4.y, acc2[0][1]);
      acc2[0][2] = fmaf(a0, w4.z, acc2[0][2]);
      acc2[0][3] = fmaf(a0, w4.w, acc2[0][3]);
      acc2[1][0] = fmaf(a1, w4.x, acc2[1][0]);
      acc2[1][1] = fmaf(a1, w4.y, acc2[1][1]);
      acc2[1][2] = fmaf(a1, w4.z, acc2[1][2]);
      acc2[1][3] = fmaf(a1, w4.w, acc2[1][3]);
    }
    // Ph layout [m][8 heads][64]
#pragma unroll
    for (int r = 0; r < 2; ++r) {
      float4 o;
      o.x = acc2[r][0]; o.y = acc2[r][1]; o.z = acc2[r][2]; o.w = acc2[r][3];
      *(float4*)&Ph[(size_t)(brow + ty * 2 + r) * 512 + head * 64 + tx * 4] = o;
    }
  }
}

// ---------------------------------------------------------------------------
// D2: layer-0 attention via Ph, head-QUARTER XCD split.
// Block b: xcd=b&7, fq=(b&7)>>1 (quarter: 2 heads), n=((b>>3)<<1)|(b&1).
// Per-XCD resident set: Ph quarter 2MB + cols ~1MB + scores -> < 4MB L2.
// One wave: lanes = (grp=lane>>5) x (hl=(lane&31)>>4) x (f4=lane&15).
// ---------------------------------------------------------------------------
__global__ __launch_bounds__(64) void attnQ_kernel(
    const float* __restrict__ Ph, const float* __restrict__ ssrc0,
    const float* __restrict__ stgt0, const int* __restrict__ deg,
    const unsigned short* __restrict__ cols, float* __restrict__ part) {
  const int b = blockIdx.x;
  const int xg = b & 7;
  const int fq = xg >> 1;               // head-quarter 0..3
  const int n = ((b >> 3) << 1) | (xg & 1);
  const int lane = threadIdx.x;         // 64 threads = 1 wave
  __shared__ int sm_[CAP];              // 1 KB
  __shared__ float sw[CAP * 3];         // 3 KB, stride 3 (coprime 32)
  const int d = deg[n];
  for (int i = lane; i < d; i += 64) sm_[i] = cols[(size_t)n * CAP + i];
  __syncthreads();
  const int hbase = fq * 2;
  const float ss0 = ssrc0[n * 8 + hbase + 0];
  const float ss1 = ssrc0[n * 8 + hbase + 1];
  for (int i = lane; i < d * 2; i += 64) {
    const int e = i >> 1, h = i & 1;
    float s = (h ? ss1 : ss0) + stgt0[sm_[e] * 8 + hbase + h];
    sw[e * 3 + h] = s >= 0.f ? s : 0.2f * s;
  }
  __syncthreads();
  float sinv[2];
#pragma unroll
  for (int h = 0; h < 2; ++h) {  // single wave owns both heads (no race)
    float mx = -1e30f;
    for (int e = lane; e < d; e += 64) mx = fmaxf(mx, sw[e * 3 + h]);
#pragma unroll
    for (int o = 32; o; o >>= 1) mx = fmaxf(mx, __shfl_xor(mx, o));
    float sum = 0.f;
    for (int e = lane; e < d; e += 64) {
      float w = __expf(sw[e * 3 + h] - mx);
      sw[e * 3 + h] = w;
      sum += w;
    }
#pragma unroll
    for (int o = 32; o; o >>= 1) sum += __shfl_xor(sum, o);
    sinv[h] = 1.0f / sum;  // full butterfly: all lanes hold it
  }
  __syncthreads();
  // gather: 512B per edge (2 heads x 64f), 2-way edge split + ILP-2
  const int grp = lane >> 5;
  const int l32 = lane & 31;
  const int hl = l32 >> 4;
  const float s = sinv[hl];
  float4 a0 = make_float4(0.f, 0.f, 0.f, 0.f), a1 = a0;
  int e = grp;
  for (; e + 2 < d; e += 4) {
    const int m0 = sm_[e], m1 = sm_[e + 2];
    const float w0 = sw[e * 3 + hl], w1 = sw[(e + 2) * 3 + hl];
    const float4 p0 =
        *(const float4*)&Ph[(size_t)m0 * 512 + fq * 128 + l32 * 4];
    const float4 p1 =
        *(const float4*)&Ph[(size_t)m1 * 512 + fq * 128 + l32 * 4];
    a0.x = fmaf(w0, p0.x, a0.x); a0.y = fmaf(w0, p0.y, a0.y);
    a0.z = fmaf(w0, p0.z, a0.z); a0.w = fmaf(w0, p0.w, a0.w);
    a1.x = fmaf(w1, p1.x, a1.x); a1.y = fmaf(w1, p1.y, a1.y);
    a1.z = fmaf(w1, p1.z, a1.z); a1.w = fmaf(w1, p1.w, a1.w);
  }
  for (; e < d; e += 2) {
    const float w = sw[e * 3 + hl];
    const float4 pv =
        *(const float4*)&Ph[(size_t)sm_[e] * 512 + fq * 128 + l32 * 4];
    a0.x = fmaf(w, pv.x, a0.x); a0.y = fmaf(w, pv.y, a0.y);
    a0.z = fmaf(w, pv.z, a0.z); a0.w = fmaf(w, pv.w, a0.w);
  }
  float4 acc;
  acc.x = (a0.x + a1.x) * s;
  acc.y = (a0.y + a1.y) * s;
  acc.z = (a0.z + a1.z) * s;
  acc.w = (a0.w + a1.w) * s;
  // reduce across hl (xor16) then grp (xor32)
#pragma unroll
  for (int o = 16; o <= 32; o <<= 1) {
    acc.x += __shfl_xor(acc.x, o);
    acc.y += __shfl_xor(acc.y, o);
    acc.z += __shfl_xor(acc.z, o);
    acc.w += __shfl_xor(acc.w, o);
  }
  if (lane < 16) {
    *(float4*)&part[(size_t)fq * (NNODES * 64) + (size_t)n * 64 + lane * 4] =
        acc;
  }
}

// ---------------------------------------------------------------------------
// D3: proj1 = part0+part1+part2+part3 + b1; fused scores1 (16-lane reduce).
// ---------------------------------------------------------------------------
__global__ __launch_bounds__(256) void finalize_scores1_kernel(
    const float* __restrict__ part, const float* __restrict__ bias,
    const float* __restrict__ a_src1, const float* __restrict__ a_tgt1,
    float* __restrict__ proj1, float* __restrict__ ssrc1,
    float* __restrict__ stgt1) {
  const int i = blockIdx.x * 256 + threadIdx.x;  // float4 idx, 65536 total
  const float4* p = (const float4*)part;
  float4 a = p[i], b = p[i + 65536], c = p[i + 131072], dd = p[i + 196608];
  const int f4 = i & 15;
  const float4 bb = *(const float4*)&bias[f4 * 4];
  float4 r;
  r.x = a.x + b.x + c.x + dd.x + bb.x;
  r.y = a.y + b.y + c.y + dd.y + bb.y;
  r.z = a.z + b.z + c.z + dd.z + bb.z;
  r.w = a.w + b.w + c.w + dd.w + bb.w;
  ((float4*)proj1)[i] = r;
  const float4 as = *(const float4*)&a_src1[f4 * 4];
  const float4 at = *(const float4*)&a_tgt1[f4 * 4];
  float ps = r.x * as.x + r.y * as.y + r.z * as.z + r.w * as.w;
  float pt = r.x * at.x + r.y * at.y + r.z * at.z + r.w * at.w;
#pragma unroll
  for (int m = 8; m; m >>= 1) {
    ps += __shfl_xor(ps, m);
    pt += __shfl_xor(pt, m);
  }
  if (f4 == 0) {
    const int node = i >> 4;
    ssrc1[node] = ps;
    stgt1[node] = pt;
  }
}

// ---------------------------------------------------------------------------
// D4: attn layer 1 (H=1): one wave per node; float4 gather, 4-way edge split.
// ---------------------------------------------------------------------------
__global__ void attn1_kernel(
    const float* __restrict__ proj, const float* __restrict__ s_src,
    const float* __restrict__ s_tgt, const int* __restrict__ deg,
    const unsigned short* __restrict__ cols, float* __restrict__ out) {
  const int n = blockIdx.x;
  const int tid = threadIdx.x;  // 64 threads = 1 wave
  __shared__ int sm_[CAP];
  __shared__ float sw[CAP];
  const int d = deg[n];
  for (int i = tid; i < d; i += 64) sm_[i] = cols[(size_t)n * CAP + i];
  __syncthreads();
  const float ssn = s_src[n];
  for (int i = tid; i < d; i += 64) {
    float s = ssn + s_tgt[sm_[i]];
    sw[i] = s >= 0.f ? s : 0.2f * s;
  }
  __syncthreads();
  float mx = -1e30f;
  for (int e = tid; e < d; e += 64) mx = fmaxf(mx, sw[e]);
#pragma unroll
  for (int o = 32; o; o >>= 1) mx = fmaxf(mx, __shfl_xor(mx, o));
  float sum = 0.f;
  for (int e = tid; e < d; e += 64) {
    float w = __expf(sw[e] - mx);
    sw[e] = w;
    sum += w;
  }
#pragma unroll
  for (int o = 32; o; o >>= 1) sum += __shfl_xor(sum, o);
  const float sinv = 1.0f / sum;
  __syncthreads();
  const int f4 = tid & 15, grp = tid >> 4;  // 16 float4 outputs, 4-way edges
  float4 acc = make_float4(0.f, 0.f, 0.f, 0.f);
  for (int e = grp; e < d; e += 4) {
    const float w = sw[e];
    const float4 pv = *(const float4*)&proj[(size_t)sm_[e] * 64 + f4 * 4];
    acc.x = fmaf(w, pv.x, acc.x);
    acc.y = fmaf(w, pv.y, acc.y);
    acc.z = fmaf(w, pv.z, acc.z);
    acc.w = fmaf(w, pv.w, acc.w);
  }
#pragma unroll
  for (int o = 16; o <= 32; o <<= 1) {
    acc.x += __shfl_xor(acc.x, o);
    acc.y += __shfl_xor(acc.y, o);
    acc.z += __shfl_xor(acc.z, o);
    acc.w += __shfl_xor(acc.w, o);
  }
  if (grp == 0) {
    acc.x *= sinv; acc.y *= sinv; acc.z *= sinv; acc.w *= sinv;
    *(float4*)&out[(size_t)n * 64 + f4 * 4] = acc;
  }
}

// ---------------------------------------------------------------------------
extern "C" void kernel_launch(void* const* d_in, const int* in_sizes, int n_in,
                              void* d_out, int out_size, void* d_ws, size_t ws_size,
                              hipStream_t stream) {
  const float* x      = (const float*)d_in[0];
  const float* mask   = (const float*)d_in[1];
  const float* W0     = (const float*)d_in[2];
  const float* b0     = (const float*)d_in[3];
  const float* a_src0 = (const float*)d_in[4];
  const float* a_tgt0 = (const float*)d_in[5];
  const float* W1     = (const float*)d_in[6];
  const float* b1     = (const float*)d_in[7];
  const float* a_src1 = (const float*)d_in[8];
  const float* a_tgt1 = (const float*)d_in[9];
  float* out = (float*)d_out;

  // workspace layout (~16.6 MB)
  float* ws    = (float*)d_ws;
  float* Ph    = ws;                          // 4096*512 (8 MB)
  float* part  = Ph + NNODES * 512;           // 4*4096*64 (4 MB)
  float* proj1 = part + 4 * NNODES * 64;      // 4096*64
  float* ssrc0 = proj1 + NNODES * 64;         // 4096*8
  float* stgt0 = ssrc0 + NNODES * 8;          // 4096*8
  float* ssrc1 = stgt0 + NNODES * 8;          // 4096
  float* stgt1 = ssrc1 + NNODES;              // 4096
  int* deg = (int*)(stgt1 + NNODES);          // 4096
  unsigned short* cols = (unsigned short*)(deg + NNODES);  // 4096*CAP u16 (2MB)

  // D1: gemm0+scores0+Ph (first 1024 blocks) + edge extraction (4096 blocks)
  phase1_kernel<<<NNODES + 1024, 256, 0, stream>>>(
      mask, deg, cols, x, W0, b0, a_src0, a_tgt0, W1, Ph, ssrc0, stgt0);
  // D2: layer-0 attention -> part quarters (head-quarter XCD split)
  attnQ_kernel<<<NNODES * 4, 64, 0, stream>>>(Ph, ssrc0, stgt0, deg, cols, part);
  // D3: proj1 = sum(part) + b1, scores1
  finalize_scores1_kernel<<<256, 256, 0, stream>>>(part, b1, a_src1, a_tgt1,
                                                   proj1, ssrc1, stgt1);
  // D4: attn layer 1
  attn1_kernel<<<NNODES, 64, 0, stream>>>(proj1, ssrc1, stgt1, deg, cols, out);
}